// Round 3
// baseline (285.670 us; speedup 1.0000x reference)
//
#include <hip/hip_runtime.h>
#include <stdint.h>

// Problem constants
#define D_DIM 512
#define K_CB  4096
#define N_TOK 16384
#define TOPK  8

// Fused kernel: 64 tokens/block, 1024 threads (16 waves), 4 passes of 1024 centroids
#define TOKB  64
#define NPASS 4
#define NSEL  16   // fp8-selected candidates that get exact fp32 rescore (e fits 4 bits)

typedef __attribute__((ext_vector_type(4)))  int    i32x4;
typedef __attribute__((ext_vector_type(8)))  int    i32x8;
typedef __attribute__((ext_vector_type(16))) float  f32x16;
typedef __attribute__((ext_vector_type(4)))  float  f32x4;

// branchless top-N insert: N x (v_max_u32 + v_min_u32)
template<int N>
__device__ __forceinline__ void inskey(unsigned int k, unsigned int (&ts)[N]) {
    #pragma unroll
    for (int q = 0; q < N; ++q) {
        unsigned int hi = ts[q] > k ? ts[q] : k;
        unsigned int lo = ts[q] > k ? k : ts[q];
        ts[q] = hi; k = lo;
    }
}

// cbf8 = fp8(e4m3) of 64*codebook in 32x32x64-MFMA-A-fragment order, 16B-chunk-split:
// group g (32 rows), step s (64 k): 2048 B = [lo16B of lane 0..63][hi16B of lane 0..63],
// lane = (k>>5 within step)*32 + row, byte j = k&31.
__global__ __launch_bounds__(256) void conv_cb_kernel(
    const float* __restrict__ cb, unsigned char* __restrict__ cbf8,
    float* __restrict__ cnorm, float* __restrict__ loss,
    unsigned int* __restrict__ ticket) {
    const int t = threadIdx.x, g = blockIdx.x;       // g: 32-row group 0..127
    if (g == 0 && t == 0) { *loss = 0.f; *ticket = 0u; }
    const int r = t >> 3, s = t & 7;                 // row 0..31, k-step 0..7
    const float* src = cb + ((size_t)(g * 32 + r)) * D_DIM + s * 64;
    float sq = 0.f;
    unsigned int d[16];
    #pragma unroll
    for (int i = 0; i < 16; ++i) {
        float4 v = ((const float4*)src)[i];
        sq += v.x*v.x + v.y*v.y + v.z*v.z + v.w*v.w;
        int dd = __builtin_amdgcn_cvt_pk_fp8_f32(64.f * v.x, 64.f * v.y, 0, false);
        dd     = __builtin_amdgcn_cvt_pk_fp8_f32(64.f * v.z, 64.f * v.w, dd, true);
        d[i] = (unsigned int)dd;
    }
    sq += __shfl_down(sq, 4, 8);
    sq += __shfl_down(sq, 2, 8);
    sq += __shfl_down(sq, 1, 8);
    if (s == 0) cnorm[g * 32 + r] = sq;              // raw ||c||^2 (exact rescore uses it)
    unsigned char* dst = cbf8 + (size_t)g * 16384 + (size_t)s * 2048;
    i32x4 w0 = {(int)d[0],  (int)d[1],  (int)d[2],  (int)d[3]};   // khalf0, j 0..15
    i32x4 w1 = {(int)d[4],  (int)d[5],  (int)d[6],  (int)d[7]};   // khalf0, j 16..31
    i32x4 w2 = {(int)d[8],  (int)d[9],  (int)d[10], (int)d[11]};  // khalf1, j 0..15
    i32x4 w3 = {(int)d[12], (int)d[13], (int)d[14], (int)d[15]};  // khalf1, j 16..31
    *(i32x4*)(dst +        (size_t)r * 16)        = w0;
    *(i32x4*)(dst + 1024 + (size_t)r * 16)        = w1;
    *(i32x4*)(dst +        (size_t)(32 + r) * 16) = w2;
    *(i32x4*)(dst + 1024 + (size_t)(32 + r) * 16) = w3;
}

// Fused: A = fp8(64c) centroids (coalesced fragment-ordered global), B = fp8(16x)
// tokens (LDS, fragment-ordered chunk-split: conflict-free b128 reads), MX-scale MFMA
// K=64 with unit scales, biased-key top-16 selection, exact fp32 rescore of 16,
// exact top-8 + softmax on exact scores, decode.
__global__ __launch_bounds__(1024) void vq_fused(
    const float* __restrict__ x, const float* __restrict__ cb,
    const unsigned char* __restrict__ cbf8, const float* __restrict__ cnorm,
    float* __restrict__ out, float* __restrict__ loss_acc,
    unsigned int* __restrict__ ticket)
{
    __shared__ union {
        unsigned char xs8[TOKB * D_DIM];             // 32768 B: fp8(16x), B-fragment order
        unsigned int  keys[256 * 64];                // 65536 B: [list*8+e][token]
    } u;
    __shared__ float ncn[K_CB];                      // 16384 B: 32768 - 512*||c||^2
    __shared__ unsigned int pk[64 * 64];             // 16 KB: stage-1 partials, depth 16
    __shared__ int   tki[TOKB * NSEL];               // 4 KB
    __shared__ float tks[TOKB * NSEL];               // 4 KB
    __shared__ float tkw[TOKB * TOPK];
    __shared__ int   tkif[TOKB * TOPK];
    __shared__ float redbuf[16];

    const int t    = threadIdx.x;
    const int lane = t & 63;
    const int w    = t >> 6;          // wave 0..15
    const int m32  = lane & 31;
    const int half = lane >> 5;
    const int tok0 = blockIdx.x * TOKB;

    // ---- stage xs8 in B-fragment order (fp8 of 16*x), 16B-chunk-split ----
    // thread: token = t>>4, k-chunk c = t&15 (32 consecutive k)
    {
        const int token = t >> 4, c = t & 15;
        const int s2 = c >> 1, lh = c & 1;
        const f32x4* src = (const f32x4*)(x + (size_t)(tok0 + token) * D_DIM + c * 32);
        unsigned int d[8];
        #pragma unroll
        for (int i = 0; i < 8; ++i) {
            f32x4 v = src[i];
            int dd = __builtin_amdgcn_cvt_pk_fp8_f32(16.f * v.x, 16.f * v.y, 0, false);
            dd     = __builtin_amdgcn_cvt_pk_fp8_f32(16.f * v.z, 16.f * v.w, dd, true);
            d[i] = (unsigned int)dd;
        }
        const int lf = lh * 32 + (token & 31);
        unsigned char* base = u.xs8 + (token >> 5) * 16384 + s2 * 2048 + lf * 16;
        i32x4 lo = {(int)d[0], (int)d[1], (int)d[2], (int)d[3]};   // j 0..15
        i32x4 hi = {(int)d[4], (int)d[5], (int)d[6], (int)d[7]};   // j 16..31
        *(i32x4*)(base)        = lo;
        *(i32x4*)(base + 1024) = hi;
    }
    {   // ncn = 32768 - 512*||c||^2 => key = 512*(2xc - ||c||^2) + 32768 > 0
        float4 v = ((const float4*)cnorm)[t];
        float4 nv = {32768.f - 512.f * v.x, 32768.f - 512.f * v.y,
                     32768.f - 512.f * v.z, 32768.f - 512.f * v.w};
        *(float4*)&ncn[t * 4] = nv;
    }
    __syncthreads();

    unsigned int ts0[8], ts1[8];      // token m32 / token 32+m32
    #pragma unroll
    for (int i = 0; i < 8; ++i) { ts0[i] = 0u; ts1[i] = 0u; }

    const char* ab0 = (const char*)cbf8 + (size_t)(w * 2) * 16384 + (size_t)lane * 16;
    const unsigned char* pb = u.xs8 + lane * 16;

    for (int pp = 0; pp < NPASS; ++pp) {
        const int p  = (pp + w) & 3;                 // stagger waves across passes
        const int ga = p * 32 + w * 2;               // centroid 32-group pair (ga, ga+1)
        f32x16 a00, a01, a10, a11;
        #pragma unroll
        for (int g = 0; g < 4; ++g) {                // acc init (LDS bcast)
            float4 n0 = *(const float4*)&ncn[ga * 32 + g * 8 + 4 * half];
            float4 n1 = *(const float4*)&ncn[ga * 32 + 32 + g * 8 + 4 * half];
            a00[g*4+0]=n0.x; a00[g*4+1]=n0.y; a00[g*4+2]=n0.z; a00[g*4+3]=n0.w;
            a01[g*4+0]=n0.x; a01[g*4+1]=n0.y; a01[g*4+2]=n0.z; a01[g*4+3]=n0.w;
            a10[g*4+0]=n1.x; a10[g*4+1]=n1.y; a10[g*4+2]=n1.z; a10[g*4+3]=n1.w;
            a11[g*4+0]=n1.x; a11[g*4+1]=n1.y; a11[g*4+2]=n1.z; a11[g*4+3]=n1.w;
        }
        const char* ab = ab0 + (size_t)p * 524288;   // p*32 groups * 16 KB
        __builtin_amdgcn_s_setprio(1);
        #pragma unroll
        for (int s = 0; s < 8; ++s) {                // K = 8 steps x 64
            i32x4 al0 = *(const i32x4*)(ab + s * 2048);
            i32x4 ah0 = *(const i32x4*)(ab + s * 2048 + 1024);
            i32x4 al1 = *(const i32x4*)(ab + s * 2048 + 16384);
            i32x4 ah1 = *(const i32x4*)(ab + s * 2048 + 17408);
            i32x4 bl0 = *(const i32x4*)(pb + s * 2048);
            i32x4 bh0 = *(const i32x4*)(pb + s * 2048 + 1024);
            i32x4 bl1 = *(const i32x4*)(pb + s * 2048 + 16384);
            i32x4 bh1 = *(const i32x4*)(pb + s * 2048 + 17408);
            i32x8 A0 = __builtin_shufflevector(al0, ah0, 0,1,2,3,4,5,6,7);
            i32x8 A1 = __builtin_shufflevector(al1, ah1, 0,1,2,3,4,5,6,7);
            i32x8 B0 = __builtin_shufflevector(bl0, bh0, 0,1,2,3,4,5,6,7);
            i32x8 B1 = __builtin_shufflevector(bl1, bh1, 0,1,2,3,4,5,6,7);
            a00 = __builtin_amdgcn_mfma_scale_f32_32x32x64_f8f6f4(
                      A0, B0, a00, 0, 0, 0, 0x7F7F7F7F, 0, 0x7F7F7F7F);
            a01 = __builtin_amdgcn_mfma_scale_f32_32x32x64_f8f6f4(
                      A0, B1, a01, 0, 0, 0, 0x7F7F7F7F, 0, 0x7F7F7F7F);
            a10 = __builtin_amdgcn_mfma_scale_f32_32x32x64_f8f6f4(
                      A1, B0, a10, 0, 0, 0, 0x7F7F7F7F, 0, 0x7F7F7F7F);
            a11 = __builtin_amdgcn_mfma_scale_f32_32x32x64_f8f6f4(
                      A1, B1, a11, 0, 0, 0, 0x7F7F7F7F, 0, 0x7F7F7F7F);
        }
        __builtin_amdgcn_s_setprio(0);
        // biased keys: scores ~[27e3,38e3] > 0 => uint-ordered; low 12 bits = 4095-idx
        const unsigned int K0 = 4095u - (unsigned int)(ga * 32) - 4u * (unsigned int)half;
        #pragma unroll
        for (int r = 0; r < 16; ++r) {
            const unsigned int cr = (unsigned int)((r & 3) + 8 * (r >> 2));
            inskey((__float_as_uint(a00[r]) & 0xFFFFF000u) | (K0 - cr),       ts0);
            inskey((__float_as_uint(a01[r]) & 0xFFFFF000u) | (K0 - cr),       ts1);
            inskey((__float_as_uint(a10[r]) & 0xFFFFF000u) | (K0 - 32u - cr), ts0);
            inskey((__float_as_uint(a11[r]) & 0xFFFFF000u) | (K0 - 32u - cr), ts1);
        }
    }

    // ---- epilogue ----
    __syncthreads();   // xs8 dead -> keys
    {
        const int kk = (w * 2 + half) * 8;           // list id 0..31, 8 keys each
        #pragma unroll
        for (int e = 0; e < 8; ++e) {
            u.keys[(kk + e) * 64 + m32]      = ts0[e];
            u.keys[(kk + e) * 64 + 32 + m32] = ts1[e];
        }
    }
    __syncthreads();
    if (t < 256) {     // stage 1: 4 threads/token, 64 keys each -> top-16 partials
        const int token = t >> 2, sub = t & 3;
        unsigned int bs[16];
        #pragma unroll
        for (int i = 0; i < 16; ++i) bs[i] = 0u;
        #pragma unroll 2
        for (int k = 0; k < 64; ++k) inskey(u.keys[(sub * 64 + k) * 64 + token], bs);
        #pragma unroll
        for (int e = 0; e < 16; ++e) pk[token * 64 + sub * 16 + e] = bs[e];
    }
    __syncthreads();
    if (t < TOKB) {    // stage 2: top-16 fp8 candidates, decode indices
        unsigned int bs[NSEL];
        #pragma unroll
        for (int i = 0; i < NSEL; ++i) bs[i] = 0u;
        #pragma unroll 2
        for (int k = 0; k < 64; ++k) inskey(pk[t * 64 + k], bs);
        #pragma unroll
        for (int r = 0; r < NSEL; ++r) tki[t * NSEL + r] = 4095 - (int)(bs[r] & 0xFFFu);
    }
    __syncthreads();
    {   // exact fp32 rescore of 16 candidates: 16 threads/token, x row read ONCE,
        // two halves of 8 to bound register pressure; coalesced interleaved float4s
        const int token = t >> 4, sl = t & 15;
        const f32x4* xr = (const f32x4*)(x + (size_t)(tok0 + token) * D_DIM);
        f32x4 xv[8];
        #pragma unroll
        for (int i = 0; i < 8; ++i) xv[i] = xr[sl + 16 * i];
        #pragma unroll
        for (int hh = 0; hh < 2; ++hh) {
            float pd[8];
            #pragma unroll
            for (int e = 0; e < 8; ++e) {
                const int idx = tki[token * NSEL + hh * 8 + e];
                const f32x4* cr = (const f32x4*)(cb + (size_t)idx * D_DIM);
                float dot = 0.f;
                #pragma unroll
                for (int i = 0; i < 8; ++i) {
                    f32x4 cv = cr[sl + 16 * i];
                    dot += xv[i].x*cv.x + xv[i].y*cv.y + xv[i].z*cv.z + xv[i].w*cv.w;
                }
                pd[e] = dot;
            }
            #pragma unroll
            for (int e = 0; e < 8; ++e) {
                pd[e] += __shfl_down(pd[e], 8, 16);
                pd[e] += __shfl_down(pd[e], 4, 16);
                pd[e] += __shfl_down(pd[e], 2, 16);
                pd[e] += __shfl_down(pd[e], 1, 16);
            }
            if (sl == 0) {
                #pragma unroll
                for (int e = 0; e < 8; ++e)
                    tks[token * NSEL + hh * 8 + e] =
                        2.f * pd[e] - cnorm[tki[token * NSEL + hh * 8 + e]];
            }
        }
    }
    __syncthreads();
    if (t < TOKB) {    // exact top-8 of the 16, softmax on exact scores
        unsigned int bs[8];
        #pragma unroll
        for (int i = 0; i < 8; ++i) bs[i] = 0u;
        #pragma unroll
        for (int e = 0; e < NSEL; ++e) {
            unsigned int uu = __float_as_uint(tks[t * NSEL + e]);
            uu ^= (unsigned int)((int)uu >> 31) | 0x80000000u;   // monotone float->uint
            inskey((uu & 0xFFFFFFF0u) | (unsigned int)e, bs);
        }
        const float m = tks[t * NSEL + (int)(bs[0] & 15u)];
        float wv[TOPK], sum = 0.f;
        int ids[TOPK];
        #pragma unroll
        for (int r = 0; r < TOPK; ++r) {
            const int e = (int)(bs[r] & 15u);
            wv[r] = __expf(tks[t * NSEL + e] - m); sum += wv[r];
            ids[r] = tki[t * NSEL + e];
        }
        const float inv = 1.f / sum;
        #pragma unroll
        for (int r = 0; r < TOPK; ++r) {
            tkw[t * TOPK + r] = wv[r] * inv;
            tkif[t * TOPK + r] = ids[r];
        }
    }
    __syncthreads();
    // output + loss partial
    float lsum = 0.f;
    #pragma unroll 1
    for (int it = 0; it < (TOKB * (D_DIM / 4)) / 1024; ++it) {   // 8 iters
        const int p = it * 1024 + t;
        const int token = p >> 7, d4 = p & 127;
        float4 q = {0.f, 0.f, 0.f, 0.f};
        #pragma unroll
        for (int e = 0; e < TOPK; ++e) {
            const float wv = tkw[token * TOPK + e];
            const int  idx = tkif[token * TOPK + e];
            const float4 cv = ((const float4*)cb)[(size_t)idx * (D_DIM / 4) + d4];
            q.x += wv * cv.x; q.y += wv * cv.y; q.z += wv * cv.z; q.w += wv * cv.w;
        }
        const size_t go = (size_t)(tok0 + token) * (D_DIM / 4) + d4;
        f32x4 xv = __builtin_nontemporal_load((const f32x4*)x + go);
        const float ex = q.x - xv.x, ey = q.y - xv.y, ez = q.z - xv.z, ew = q.w - xv.w;
        lsum += ex*ex + ey*ey + ez*ez + ew*ew;
        f32x4 qv = {q.x, q.y, q.z, q.w};
        __builtin_nontemporal_store(qv, (f32x4*)out + go);
    }
    #pragma unroll
    for (int off = 32; off > 0; off >>= 1) lsum += __shfl_down(lsum, off, 64);
    if (lane == 0) redbuf[w] = lsum;
    __syncthreads();
    if (t == 0) {
        float s = 0.f;
        #pragma unroll
        for (int i = 0; i < 16; ++i) s += redbuf[i];
        atomicAdd(loss_acc, s);
        __threadfence();
        unsigned int prev = atomicAdd(ticket, 1u);
        if (prev == (unsigned int)(gridDim.x - 1)) {   // last block finalizes loss
            __threadfence();
            float total = atomicAdd(loss_acc, 0.f);    // coherent read
            out[(size_t)N_TOK * D_DIM] = 1.25f * total / (float)((size_t)N_TOK * D_DIM);
        }
    }
}

extern "C" void kernel_launch(void* const* d_in, const int* in_sizes, int n_in,
                              void* d_out, int out_size, void* d_ws, size_t ws_size,
                              hipStream_t stream) {
    const float* x  = (const float*)d_in[0];   // [8,2048,512] fp32
    const float* cb = (const float*)d_in[1];   // [4096,512] fp32
    float* out = (float*)d_out;

    char* ws = (char*)d_ws;
    unsigned char* cbf8   = (unsigned char*)ws;              // 2 MB, fp8 fragment-ordered
    float*         cnorm  = (float*)(ws + 2097152);          // 16 KB
    float*         loss   = (float*)(ws + 2113536);          // 4 B
    unsigned int*  ticket = (unsigned int*)(ws + 2113600);   // 4 B

    conv_cb_kernel<<<128, 256, 0, stream>>>(cb, cbf8, cnorm, loss, ticket);
    vq_fused<<<N_TOK / TOKB, 1024, 0, stream>>>(x, cb, cbf8, cnorm, out, loss, ticket);
}

// Round 4
// 228.224 us; speedup vs baseline: 1.2517x; 1.2517x over previous
//
#include <hip/hip_runtime.h>
#include <stdint.h>

// Problem constants
#define D_DIM 512
#define K_CB  4096
#define N_TOK 16384
#define TOPK  8

// Fused kernel: 64 tokens/block, 1024 threads (16 waves), 8 passes of 512 centroids
#define TOKB  64
#define NPASS 8
#define NSEL  16   // fp8-selected candidates that get exact fp32 rescore (e fits 4 bits)

typedef __attribute__((ext_vector_type(4)))  int    i32x4;
typedef __attribute__((ext_vector_type(8)))  int    i32x8;
typedef __attribute__((ext_vector_type(16))) float  f32x16;
typedef __attribute__((ext_vector_type(4)))  float  f32x4;

// branchless top-N insert: N x (v_max_u32 + v_min_u32)
template<int N>
__device__ __forceinline__ void inskey(unsigned int k, unsigned int (&ts)[N]) {
    #pragma unroll
    for (int q = 0; q < N; ++q) {
        unsigned int hi = ts[q] > k ? ts[q] : k;
        unsigned int lo = ts[q] > k ? k : ts[q];
        ts[q] = hi; k = lo;
    }
}

// cbf8 = fp8(e4m3) of 64*codebook in 32x32x64-MFMA-A-fragment order, 16B-chunk-split:
// group g (32 rows), step s (64 k): 2048 B = [lo16B of lane 0..63][hi16B of lane 0..63],
// lane = (k>>5 within step)*32 + row, byte j = k&31.
__global__ __launch_bounds__(256) void conv_cb_kernel(
    const float* __restrict__ cb, unsigned char* __restrict__ cbf8,
    float* __restrict__ cnorm, float* __restrict__ loss,
    unsigned int* __restrict__ ticket) {
    const int t = threadIdx.x, g = blockIdx.x;       // g: 32-row group 0..127
    if (g == 0 && t == 0) { *loss = 0.f; *ticket = 0u; }
    const int r = t >> 3, s = t & 7;                 // row 0..31, k-step 0..7
    const float* src = cb + ((size_t)(g * 32 + r)) * D_DIM + s * 64;
    float sq = 0.f;
    unsigned int d[16];
    #pragma unroll
    for (int i = 0; i < 16; ++i) {
        float4 v = ((const float4*)src)[i];
        sq += v.x*v.x + v.y*v.y + v.z*v.z + v.w*v.w;
        int dd = __builtin_amdgcn_cvt_pk_fp8_f32(64.f * v.x, 64.f * v.y, 0, false);
        dd     = __builtin_amdgcn_cvt_pk_fp8_f32(64.f * v.z, 64.f * v.w, dd, true);
        d[i] = (unsigned int)dd;
    }
    sq += __shfl_down(sq, 4, 8);
    sq += __shfl_down(sq, 2, 8);
    sq += __shfl_down(sq, 1, 8);
    if (s == 0) cnorm[g * 32 + r] = sq;              // raw ||c||^2 (exact rescore uses it)
    unsigned char* dst = cbf8 + (size_t)g * 16384 + (size_t)s * 2048;
    i32x4 w0 = {(int)d[0],  (int)d[1],  (int)d[2],  (int)d[3]};   // khalf0, j 0..15
    i32x4 w1 = {(int)d[4],  (int)d[5],  (int)d[6],  (int)d[7]};   // khalf0, j 16..31
    i32x4 w2 = {(int)d[8],  (int)d[9],  (int)d[10], (int)d[11]};  // khalf1, j 0..15
    i32x4 w3 = {(int)d[12], (int)d[13], (int)d[14], (int)d[15]};  // khalf1, j 16..31
    *(i32x4*)(dst +        (size_t)r * 16)        = w0;
    *(i32x4*)(dst + 1024 + (size_t)r * 16)        = w1;
    *(i32x4*)(dst +        (size_t)(32 + r) * 16) = w2;
    *(i32x4*)(dst + 1024 + (size_t)(32 + r) * 16) = w3;
}

// Fused: A = fp8(64c) centroids (coalesced fragment-ordered global), B = fp8(16x)
// tokens (LDS, fragment-ordered chunk-split: conflict-free b128 reads), MX-scale MFMA
// K=64 with unit scales. 1A x 2B tile (32 AGPR) x 8 passes -- fits the 128-reg/lane
// budget at 16 waves/CU without scratch spill (round-3 post-mortem: 2A x 2B spilled,
// +145 MB sym. R/W). Biased-key top-16 selection, exact fp32 rescore of 16,
// exact top-8 + softmax on exact scores, decode.
__global__ __launch_bounds__(1024) void vq_fused(
    const float* __restrict__ x, const float* __restrict__ cb,
    const unsigned char* __restrict__ cbf8, const float* __restrict__ cnorm,
    float* __restrict__ out, float* __restrict__ loss_acc,
    unsigned int* __restrict__ ticket)
{
    __shared__ union {
        unsigned char xs8[TOKB * D_DIM];             // 32768 B: fp8(16x), B-fragment order
        unsigned int  keys[256 * 64];                // 65536 B: [list*8+e][token]
    } u;
    __shared__ float ncn[K_CB];                      // 16384 B: 32768 - 512*||c||^2
    __shared__ unsigned int pk[64 * 64];             // 16 KB: stage-1 partials, depth 16
    __shared__ int   tki[TOKB * NSEL];               // 4 KB
    __shared__ float tks[TOKB * NSEL];               // 4 KB
    __shared__ float tkw[TOKB * TOPK];
    __shared__ int   tkif[TOKB * TOPK];
    __shared__ float redbuf[16];

    const int t    = threadIdx.x;
    const int lane = t & 63;
    const int w    = t >> 6;          // wave 0..15
    const int m32  = lane & 31;
    const int half = lane >> 5;
    const int tok0 = blockIdx.x * TOKB;

    // ---- stage xs8 in B-fragment order (fp8 of 16*x), 16B-chunk-split ----
    // thread: token = t>>4, k-chunk c = t&15 (32 consecutive k)
    {
        const int token = t >> 4, c = t & 15;
        const int s2 = c >> 1, lh = c & 1;
        const f32x4* src = (const f32x4*)(x + (size_t)(tok0 + token) * D_DIM + c * 32);
        unsigned int d[8];
        #pragma unroll
        for (int i = 0; i < 8; ++i) {
            f32x4 v = src[i];
            int dd = __builtin_amdgcn_cvt_pk_fp8_f32(16.f * v.x, 16.f * v.y, 0, false);
            dd     = __builtin_amdgcn_cvt_pk_fp8_f32(16.f * v.z, 16.f * v.w, dd, true);
            d[i] = (unsigned int)dd;
        }
        const int lf = lh * 32 + (token & 31);
        unsigned char* base = u.xs8 + (token >> 5) * 16384 + s2 * 2048 + lf * 16;
        i32x4 lo = {(int)d[0], (int)d[1], (int)d[2], (int)d[3]};   // j 0..15
        i32x4 hi = {(int)d[4], (int)d[5], (int)d[6], (int)d[7]};   // j 16..31
        *(i32x4*)(base)        = lo;
        *(i32x4*)(base + 1024) = hi;
    }
    {   // ncn = 32768 - 512*||c||^2 => key = 512*(2xc - ||c||^2) + 32768 > 0
        float4 v = ((const float4*)cnorm)[t];
        float4 nv = {32768.f - 512.f * v.x, 32768.f - 512.f * v.y,
                     32768.f - 512.f * v.z, 32768.f - 512.f * v.w};
        *(float4*)&ncn[t * 4] = nv;
    }
    __syncthreads();

    unsigned int ts0[8], ts1[8];      // token m32 / token 32+m32
    #pragma unroll
    for (int i = 0; i < 8; ++i) { ts0[i] = 0u; ts1[i] = 0u; }

    const char* ab0 = (const char*)cbf8 + (size_t)w * 16384 + (size_t)lane * 16;
    const unsigned char* pb = u.xs8 + lane * 16;

    for (int pp = 0; pp < NPASS; ++pp) {
        const int p  = (pp + w) & 7;                 // stagger waves across passes
        const int ga = p * 16 + w;                   // centroid 32-group 0..127
        f32x16 a0, a1;
        #pragma unroll
        for (int g = 0; g < 4; ++g) {                // acc init (LDS bcast)
            float4 n0 = *(const float4*)&ncn[ga * 32 + g * 8 + 4 * half];
            a0[g*4+0]=n0.x; a0[g*4+1]=n0.y; a0[g*4+2]=n0.z; a0[g*4+3]=n0.w;
            a1[g*4+0]=n0.x; a1[g*4+1]=n0.y; a1[g*4+2]=n0.z; a1[g*4+3]=n0.w;
        }
        const char* ab = ab0 + (size_t)p * 262144;   // p*16 groups * 16 KB
        __builtin_amdgcn_s_setprio(1);
        #pragma unroll 2
        for (int s = 0; s < 8; ++s) {                // K = 8 steps x 64
            i32x4 al = *(const i32x4*)(ab + s * 2048);
            i32x4 ah = *(const i32x4*)(ab + s * 2048 + 1024);
            i32x4 bl0 = *(const i32x4*)(pb + s * 2048);
            i32x4 bh0 = *(const i32x4*)(pb + s * 2048 + 1024);
            i32x4 bl1 = *(const i32x4*)(pb + s * 2048 + 16384);
            i32x4 bh1 = *(const i32x4*)(pb + s * 2048 + 17408);
            i32x8 A  = __builtin_shufflevector(al,  ah,  0,1,2,3,4,5,6,7);
            i32x8 B0 = __builtin_shufflevector(bl0, bh0, 0,1,2,3,4,5,6,7);
            i32x8 B1 = __builtin_shufflevector(bl1, bh1, 0,1,2,3,4,5,6,7);
            a0 = __builtin_amdgcn_mfma_scale_f32_32x32x64_f8f6f4(
                     A, B0, a0, 0, 0, 0, 0x7F7F7F7F, 0, 0x7F7F7F7F);
            a1 = __builtin_amdgcn_mfma_scale_f32_32x32x64_f8f6f4(
                     A, B1, a1, 0, 0, 0, 0x7F7F7F7F, 0, 0x7F7F7F7F);
        }
        __builtin_amdgcn_s_setprio(0);
        // biased keys: scores ~[27e3,38e3] > 0 => uint-ordered; low 12 bits = 4095-idx
        const unsigned int K0 = 4095u - (unsigned int)(ga * 32) - 4u * (unsigned int)half;
        #pragma unroll
        for (int r = 0; r < 16; ++r) {
            const unsigned int cr = (unsigned int)((r & 3) + 8 * (r >> 2));
            inskey((__float_as_uint(a0[r]) & 0xFFFFF000u) | (K0 - cr), ts0);
            inskey((__float_as_uint(a1[r]) & 0xFFFFF000u) | (K0 - cr), ts1);
        }
    }

    // ---- epilogue ----
    __syncthreads();   // xs8 dead -> keys
    {
        const int kk = (w * 2 + half) * 8;           // list id 0..31, 8 keys each
        #pragma unroll
        for (int e = 0; e < 8; ++e) {
            u.keys[(kk + e) * 64 + m32]      = ts0[e];
            u.keys[(kk + e) * 64 + 32 + m32] = ts1[e];
        }
    }
    __syncthreads();
    if (t < 256) {     // stage 1: 4 threads/token, 64 keys each -> top-16 partials
        const int token = t >> 2, sub = t & 3;
        unsigned int bs[16];
        #pragma unroll
        for (int i = 0; i < 16; ++i) bs[i] = 0u;
        #pragma unroll 2
        for (int k = 0; k < 64; ++k) inskey(u.keys[(sub * 64 + k) * 64 + token], bs);
        #pragma unroll
        for (int e = 0; e < 16; ++e) pk[token * 64 + sub * 16 + e] = bs[e];
    }
    __syncthreads();
    if (t < TOKB) {    // stage 2: top-16 fp8 candidates, decode indices
        unsigned int bs[NSEL];
        #pragma unroll
        for (int i = 0; i < NSEL; ++i) bs[i] = 0u;
        #pragma unroll 2
        for (int k = 0; k < 64; ++k) inskey(pk[t * 64 + k], bs);
        #pragma unroll
        for (int r = 0; r < NSEL; ++r) tki[t * NSEL + r] = 4095 - (int)(bs[r] & 0xFFFu);
    }
    __syncthreads();
    {   // exact fp32 rescore of 16 candidates: 16 threads/token, x row read ONCE,
        // two halves of 8 to bound register pressure; coalesced interleaved float4s
        const int token = t >> 4, sl = t & 15;
        const f32x4* xr = (const f32x4*)(x + (size_t)(tok0 + token) * D_DIM);
        f32x4 xv[8];
        #pragma unroll
        for (int i = 0; i < 8; ++i) xv[i] = xr[sl + 16 * i];
        #pragma unroll
        for (int hh = 0; hh < 2; ++hh) {
            float pd[8];
            #pragma unroll
            for (int e = 0; e < 8; ++e) {
                const int idx = tki[token * NSEL + hh * 8 + e];
                const f32x4* cr = (const f32x4*)(cb + (size_t)idx * D_DIM);
                float dot = 0.f;
                #pragma unroll
                for (int i = 0; i < 8; ++i) {
                    f32x4 cv = cr[sl + 16 * i];
                    dot += xv[i].x*cv.x + xv[i].y*cv.y + xv[i].z*cv.z + xv[i].w*cv.w;
                }
                pd[e] = dot;
            }
            #pragma unroll
            for (int e = 0; e < 8; ++e) {
                pd[e] += __shfl_down(pd[e], 8, 16);
                pd[e] += __shfl_down(pd[e], 4, 16);
                pd[e] += __shfl_down(pd[e], 2, 16);
                pd[e] += __shfl_down(pd[e], 1, 16);
            }
            if (sl == 0) {
                #pragma unroll
                for (int e = 0; e < 8; ++e)
                    tks[token * NSEL + hh * 8 + e] =
                        2.f * pd[e] - cnorm[tki[token * NSEL + hh * 8 + e]];
            }
        }
    }
    __syncthreads();
    if (t < TOKB) {    // exact top-8 of the 16, softmax on exact scores
        unsigned int bs[8];
        #pragma unroll
        for (int i = 0; i < 8; ++i) bs[i] = 0u;
        #pragma unroll
        for (int e = 0; e < NSEL; ++e) {
            unsigned int uu = __float_as_uint(tks[t * NSEL + e]);
            uu ^= (unsigned int)((int)uu >> 31) | 0x80000000u;   // monotone float->uint
            inskey((uu & 0xFFFFFFF0u) | (unsigned int)e, bs);
        }
        const float m = tks[t * NSEL + (int)(bs[0] & 15u)];
        float wv[TOPK], sum = 0.f;
        int ids[TOPK];
        #pragma unroll
        for (int r = 0; r < TOPK; ++r) {
            const int e = (int)(bs[r] & 15u);
            wv[r] = __expf(tks[t * NSEL + e] - m); sum += wv[r];
            ids[r] = tki[t * NSEL + e];
        }
        const float inv = 1.f / sum;
        #pragma unroll
        for (int r = 0; r < TOPK; ++r) {
            tkw[t * TOPK + r] = wv[r] * inv;
            tkif[t * TOPK + r] = ids[r];
        }
    }
    __syncthreads();
    // output + loss partial
    float lsum = 0.f;
    #pragma unroll 1
    for (int it = 0; it < (TOKB * (D_DIM / 4)) / 1024; ++it) {   // 8 iters
        const int p = it * 1024 + t;
        const int token = p >> 7, d4 = p & 127;
        float4 q = {0.f, 0.f, 0.f, 0.f};
        #pragma unroll
        for (int e = 0; e < TOPK; ++e) {
            const float wv = tkw[token * TOPK + e];
            const int  idx = tkif[token * TOPK + e];
            const float4 cv = ((const float4*)cb)[(size_t)idx * (D_DIM / 4) + d4];
            q.x += wv * cv.x; q.y += wv * cv.y; q.z += wv * cv.z; q.w += wv * cv.w;
        }
        const size_t go = (size_t)(tok0 + token) * (D_DIM / 4) + d4;
        f32x4 xv = __builtin_nontemporal_load((const f32x4*)x + go);
        const float ex = q.x - xv.x, ey = q.y - xv.y, ez = q.z - xv.z, ew = q.w - xv.w;
        lsum += ex*ex + ey*ey + ez*ez + ew*ew;
        f32x4 qv = {q.x, q.y, q.z, q.w};
        __builtin_nontemporal_store(qv, (f32x4*)out + go);
    }
    #pragma unroll
    for (int off = 32; off > 0; off >>= 1) lsum += __shfl_down(lsum, off, 64);
    if (lane == 0) redbuf[w] = lsum;
    __syncthreads();
    if (t == 0) {
        float s = 0.f;
        #pragma unroll
        for (int i = 0; i < 16; ++i) s += redbuf[i];
        atomicAdd(loss_acc, s);
        __threadfence();
        unsigned int prev = atomicAdd(ticket, 1u);
        if (prev == (unsigned int)(gridDim.x - 1)) {   // last block finalizes loss
            __threadfence();
            float total = atomicAdd(loss_acc, 0.f);    // coherent read
            out[(size_t)N_TOK * D_DIM] = 1.25f * total / (float)((size_t)N_TOK * D_DIM);
        }
    }
}

extern "C" void kernel_launch(void* const* d_in, const int* in_sizes, int n_in,
                              void* d_out, int out_size, void* d_ws, size_t ws_size,
                              hipStream_t stream) {
    const float* x  = (const float*)d_in[0];   // [8,2048,512] fp32
    const float* cb = (const float*)d_in[1];   // [4096,512] fp32
    float* out = (float*)d_out;

    char* ws = (char*)d_ws;
    unsigned char* cbf8   = (unsigned char*)ws;              // 2 MB, fp8 fragment-ordered
    float*         cnorm  = (float*)(ws + 2097152);          // 16 KB
    float*         loss   = (float*)(ws + 2113536);          // 4 B
    unsigned int*  ticket = (unsigned int*)(ws + 2113600);   // 4 B

    conv_cb_kernel<<<128, 256, 0, stream>>>(cb, cbf8, cnorm, loss, ticket);
    vq_fused<<<N_TOK / TOKB, 1024, 0, stream>>>(x, cb, cbf8, cnorm, out, loss, ticket);
}